// Round 10
// baseline (48.590 us; speedup 1.0000x reference)
//
#include <hip/hip_runtime.h>
#include <hip/hip_bf16.h>

typedef _Float16 h4 __attribute__((ext_vector_type(4)));
typedef _Float16 h8 __attribute__((ext_vector_type(8)));
typedef float f32x4 __attribute__((ext_vector_type(4)));

#define CIN 128
#define COUT 256
#define KDIM (CIN*9)   // 1152

// ---------------- merged prep + transpose ----------------
// blocks [0,256): transpose  xT[((b*64+y)*64+x)*128 + c] = fp16(x[b][c][y][x])
// blocks [256,1408): Wf[(((kch*16 + of)*64 + l)*8 + e)] = fp16(W[o=of*16+(l&15)][kc=kch*32+(l>>4)*8+e])
// blocks [1408,1552): omWf[(((kch*2 + of)*64 + l)*8 + e)] = fp16(om_w[o][c][k]), 0 if o>=27
__global__ __launch_bounds__(256) void k_pt(const float* __restrict__ x,
                                            const float* __restrict__ wgt,
                                            const float* __restrict__ om_w,
                                            unsigned short* __restrict__ xT,
                                            unsigned short* __restrict__ Wf,
                                            unsigned short* __restrict__ omWf) {
    __shared__ unsigned short tile[64][132];
    const int bid = blockIdx.x;
    if (bid < 256) {
        const int b = bid >> 6, y = bid & 63;
        const float* xp = x + (size_t)b * CIN * 4096 + y * 64;
        const int w = threadIdx.x & 63, cg = threadIdx.x >> 6;
#pragma unroll
        for (int cc = 0; cc < CIN; cc += 4) {
            int c = cc + cg;
            _Float16 hv = (_Float16)xp[(size_t)c * 4096 + w];
            tile[w][c] = *(unsigned short*)&hv;
        }
        __syncthreads();
        unsigned short* orow = xT + (size_t)(b * 4096 + y * 64) * CIN;
#pragma unroll
        for (int i = 0; i < 8; ++i) {
            int j = threadIdx.x + i * 256;
            int w2 = j >> 5, c2 = (j & 31) * 4;
            ushort4 v = *(ushort4*)&tile[w2][c2];
            ((ushort4*)orow)[j] = v;
        }
    } else if (bid < 1408) {
        int f = (bid - 256) * 256 + threadIdx.x;
        int e = f & 7, l = (f >> 3) & 63, of = (f >> 9) & 15, kch = f >> 13;
        int o = of * 16 + (l & 15);
        int kc = kch * 32 + (l >> 4) * 8 + e;
        int k = kc >> 7, c = kc & 127;
        _Float16 hv = (_Float16)wgt[(size_t)o * KDIM + c * 9 + k];
        Wf[f] = *(unsigned short*)&hv;
    } else {
        int f = (bid - 1408) * 256 + threadIdx.x;   // < 36864
        int e = f & 7, l = (f >> 3) & 63, of = (f >> 9) & 1, kch = f >> 10;
        int o = of * 16 + (l & 15);
        int c = (kch & 3) * 32 + (l >> 4) * 8 + e;
        int k = kch >> 2;
        float v = (o < 27) ? om_w[(size_t)o * KDIM + c * 9 + k] : 0.f;
        _Float16 hv = (_Float16)v;
        omWf[f] = *(unsigned short*)&hv;
    }
}

// ---------------- fused: offset-conv (MFMA) + gather + MFMA GEMM ----------------
// One block per (b, h, half): 32 positions x 256 Cout, 256 threads (4 waves).
__global__ __launch_bounds__(256, 3) void k_fused(const unsigned short* __restrict__ xT_u,
                                                  const unsigned short* __restrict__ omWf_u,
                                                  const float* __restrict__ om_b,
                                                  const unsigned short* __restrict__ Wf_u,
                                                  const float* __restrict__ bias,
                                                  float* __restrict__ out) {
    const int bid = blockIdx.x;
    const int half = bid & 1, h = (bid >> 1) & 63, b = bid >> 7;
    const int p_base = half * 32;
    const int tid = threadIdx.x;
    const int wv = tid >> 6, lane = tid & 63;
    const int khalf = lane >> 4, lr = lane & 15;

    __shared__ int   s_off[4][288];
    __shared__ float s_wt[4][288];
    __shared__ h8    s_tile[2][32 * 8];   // [buf][row*8 + swizzled slot]
    __shared__ float red[2][32][28];      // omconv partials [tapHalf][pos_local][oc]

    const _Float16* xb = (const _Float16*)xT_u + (size_t)b * (4096 * CIN);

    // ===== Phase 1: offset conv, 4 waves = 2 position-groups x 2 tap-halves =====
    // Compile-time 5-iteration unroll; the 4-tap wave (kh2=1) runs a dummy 5th
    // iteration with bf=0 (adds exact +0.0) so the compiler can pipeline loads.
    {
        const h8* Af = (const h8*)omWf_u;
        const int pg = wv & 1, kh2 = wv >> 1;
        const int pl = pg * 16 + lr;               // local position 0..31
        const int p1 = p_base + pl;
        f32x4 acc0 = (f32x4){0.f, 0.f, 0.f, 0.f};
        f32x4 acc1 = (f32x4){0.f, 0.f, 0.f, 0.f};
#pragma unroll
        for (int kk = 0; kk < 5; ++kk) {
            const bool act = !(kh2 && kk == 4);
            const int k = kh2 ? (kk == 4 ? 8 : 5 + kk) : kk;
            const int ky = k / 3, kx = k - ky * 3;
            const int y = h + ky - 1, xq = p1 + kx - 1;
            const bool valid = act && ((unsigned)y < 64u) && ((unsigned)xq < 64u);
            const _Float16* src = xb + ((y * 64 + xq) * CIN);
#pragma unroll
            for (int cg = 0; cg < 4; ++cg) {
                h8 bf = {};
                if (valid) bf = *(const h8*)(src + cg * 32 + khalf * 8);
                const int kch = k * 4 + cg;
                h8 a0 = Af[(kch * 2 + 0) * 64 + lane];
                h8 a1 = Af[(kch * 2 + 1) * 64 + lane];
                acc0 = __builtin_amdgcn_mfma_f32_16x16x32_f16(a0, bf, acc0, 0, 0, 0);
                acc1 = __builtin_amdgcn_mfma_f32_16x16x32_f16(a1, bf, acc1, 0, 0, 0);
            }
        }
        // C layout: col = lr (position), row = khalf*4 + r (+16 for acc1)
#pragma unroll
        for (int r = 0; r < 4; ++r) {
            red[kh2][pl][khalf * 4 + r] = acc0[r];
            int row1 = 16 + khalf * 4 + r;
            if (row1 < 27) red[kh2][pl][row1] = acc1[r];
        }
    }
    __syncthreads();

    // ===== Phase 2: sampling metadata for all (k, pl) =====
    for (int e = tid; e < 288; e += 256) {
        int k = e >> 5, pl = e & 31;
        int p = p_base + pl;
        float offx = red[0][pl][k]      + red[1][pl][k]      + om_b[k];
        float offy = red[0][pl][9 + k]  + red[1][pl][9 + k]  + om_b[9 + k];
        float mv   = red[0][pl][18 + k] + red[1][pl][18 + k] + om_b[18 + k];
        float mask = 1.f / (1.f + __expf(-mv));
        int ky = k / 3, kx = k - ky * 3;
        const float SC = 64.f / 63.f;
        float ix = ((float)(p + kx - 2) + offx) * SC - 0.5f;
        float iy = ((float)(h + ky - 2) + offy) * SC - 0.5f;
        float fx0 = floorf(ix), fy0 = floorf(iy);
        float wx1 = ix - fx0, wx0 = 1.f - wx1;
        float wy1 = iy - fy0, wy0 = 1.f - wy1;
        int x0 = (int)fx0, y0 = (int)fy0;
        int x1 = x0 + 1, y1 = y0 + 1;
        bool vx0 = (unsigned)x0 < 64u, vx1 = (unsigned)x1 < 64u;
        bool vy0 = (unsigned)y0 < 64u, vy1 = (unsigned)y1 < 64u;
        int xc0 = min(max(x0, 0), 63), xc1 = min(max(x1, 0), 63);
        int yc0 = min(max(y0, 0), 63), yc1 = min(max(y1, 0), 63);
        s_off[0][e] = (yc0 * 64 + xc0) * CIN;
        s_off[1][e] = (yc0 * 64 + xc1) * CIN;
        s_off[2][e] = (yc1 * 64 + xc0) * CIN;
        s_off[3][e] = (yc1 * 64 + xc1) * CIN;
        s_wt[0][e] = (vy0 && vx0) ? wy0 * wx0 * mask : 0.f;
        s_wt[1][e] = (vy0 && vx1) ? wy0 * wx1 * mask : 0.f;
        s_wt[2][e] = (vy1 && vx0) ? wy1 * wx0 * mask : 0.f;
        s_wt[3][e] = (vy1 && vx1) ? wy1 * wx1 * mask : 0.f;
    }
    __syncthreads();

    // ===== Phase 3: pipelined gather + MFMA GEMM (18 chunks of 64 ch) =====
    // Wf fragments for each chunk's ks=0 are register-prefetched one chunk
    // ahead (aE/aO ping-pong, static parity); ks=1 loads are issued before
    // the ks=0 MFMAs so their latency hides under the matrix pipe.
    const int p  = tid >> 3;      // local gather position 0..31
    const int ci = tid & 7;       // 8-channel slot
    const h8* Wf8 = (const h8*)Wf_u;
    const int wslot = ci ^ (p & 7);

    f32x4 acc[4][2];              // [of-frag i][pos-frag pf]
#pragma unroll
    for (int i = 0; i < 4; ++i)
#pragma unroll
        for (int j = 0; j < 2; ++j) acc[i][j] = (f32x4){0.f, 0.f, 0.f, 0.f};

    h8 aE[4], aO[4];

    // prologue: gather chunk 0 into buf 0 + prefetch chunk-0 ks=0 a-frags
    {
        const int e0 = p;                     // tap 0
        const int cb = ci * 8;                // chalf 0
        h8 v00 = *(const h8*)(xb + s_off[0][e0] + cb);
        h8 v01 = *(const h8*)(xb + s_off[1][e0] + cb);
        h8 v10 = *(const h8*)(xb + s_off[2][e0] + cb);
        h8 v11 = *(const h8*)(xb + s_off[3][e0] + cb);
#pragma unroll
        for (int i = 0; i < 4; ++i)
            aE[i] = Wf8[(0 * 16 + wv * 4 + i) * 64 + lane];   // kch = 0
        const float m00 = s_wt[0][e0], m01 = s_wt[1][e0], m10 = s_wt[2][e0], m11 = s_wt[3][e0];
        h8 pk;
#pragma unroll
        for (int j = 0; j < 8; ++j) {
            float r = m00 * (float)v00[j] + m01 * (float)v01[j]
                    + m10 * (float)v10[j] + m11 * (float)v11[j];
            pk[j] = (_Float16)r;
        }
        s_tile[0][p * 8 + wslot] = pk;
    }
    __syncthreads();

#define CHUNK_STEP(CH, ACUR, ANXT)                                                     \
    {                                                                                  \
        const int ch_ = (CH), cur_ = ch_ & 1, nxt_ = ch_ + 1;                          \
        h8 v00, v01, v10, v11;                                                         \
        float m00, m01, m10, m11;                                                      \
        if (nxt_ < 18) {                                                               \
            const int e = (nxt_ >> 1) * 32 + p;                                        \
            const int cb = (nxt_ & 1) * 64 + ci * 8;                                   \
            v00 = *(const h8*)(xb + s_off[0][e] + cb);                                 \
            v01 = *(const h8*)(xb + s_off[1][e] + cb);                                 \
            v10 = *(const h8*)(xb + s_off[2][e] + cb);                                 \
            v11 = *(const h8*)(xb + s_off[3][e] + cb);                                 \
            m00 = s_wt[0][e]; m01 = s_wt[1][e]; m10 = s_wt[2][e]; m11 = s_wt[3][e];    \
        }                                                                              \
        const int kchb = (ch_ >> 1) * 4 + (ch_ & 1) * 2;                               \
        h8 aI[4];                                                                      \
        _Pragma("unroll")                                                              \
        for (int i = 0; i < 4; ++i)                                                    \
            aI[i] = Wf8[((kchb + 1) * 16 + wv * 4 + i) * 64 + lane];                   \
        if (nxt_ < 18) {                                                               \
            const int kchn = (nxt_ >> 1) * 4 + (nxt_ & 1) * 2;                         \
            _Pragma("unroll")                                                          \
            for (int i = 0; i < 4; ++i)                                                \
                ANXT[i] = Wf8[(kchn * 16 + wv * 4 + i) * 64 + lane];                   \
        }                                                                              \
        h8 bf0[2], bf1[2];                                                             \
        _Pragma("unroll")                                                              \
        for (int pf = 0; pf < 2; ++pf) {                                               \
            const int row = pf * 16 + lr;                                              \
            bf0[pf] = s_tile[cur_][row * 8 + (khalf ^ (row & 7))];                     \
            bf1[pf] = s_tile[cur_][row * 8 + ((4 + khalf) ^ (row & 7))];               \
        }                                                                              \
        _Pragma("unroll")                                                              \
        for (int i = 0; i < 4; ++i)                                                    \
            _Pragma("unroll")                                                          \
            for (int pf = 0; pf < 2; ++pf)                                             \
                acc[i][pf] = __builtin_amdgcn_mfma_f32_16x16x32_f16(ACUR[i], bf0[pf], acc[i][pf], 0, 0, 0); \
        _Pragma("unroll")                                                              \
        for (int i = 0; i < 4; ++i)                                                    \
            _Pragma("unroll")                                                          \
            for (int pf = 0; pf < 2; ++pf)                                             \
                acc[i][pf] = __builtin_amdgcn_mfma_f32_16x16x32_f16(aI[i], bf1[pf], acc[i][pf], 0, 0, 0);   \
        if (nxt_ < 18) {                                                               \
            h8 pk;                                                                     \
            _Pragma("unroll")                                                          \
            for (int j = 0; j < 8; ++j) {                                              \
                float r = m00 * (float)v00[j] + m01 * (float)v01[j]                    \
                        + m10 * (float)v10[j] + m11 * (float)v11[j];                   \
                pk[j] = (_Float16)r;                                                   \
            }                                                                          \
            s_tile[cur_ ^ 1][p * 8 + wslot] = pk;                                      \
        }                                                                              \
        __syncthreads();                                                               \
    }

#pragma unroll
    for (int cp = 0; cp < 9; ++cp) {
        CHUNK_STEP(2 * cp,     aE, aO)
        CHUNK_STEP(2 * cp + 1, aO, aE)
    }
#undef CHUNK_STEP

    // epilogue: C[o = wv*64 + i*16 + khalf*4 + r][pos = p_base + pf*16 + lr]
    float* outb = out + (size_t)b * COUT * 4096 + h * 64 + p_base;
#pragma unroll
    for (int i = 0; i < 4; ++i) {
#pragma unroll
        for (int r = 0; r < 4; ++r) {
            const int o = wv * 64 + i * 16 + khalf * 4 + r;
            const float bo = bias[o];
            float* orow = outb + (size_t)o * 4096;
#pragma unroll
            for (int pf = 0; pf < 2; ++pf)
                orow[pf * 16 + lr] = acc[i][pf][r] + bo;
        }
    }
}

extern "C" void kernel_launch(void* const* d_in, const int* in_sizes, int n_in,
                              void* d_out, int out_size, void* d_ws, size_t ws_size,
                              hipStream_t stream) {
    const float* x    = (const float*)d_in[0];
    const float* om_w = (const float*)d_in[1];
    const float* om_b = (const float*)d_in[2];
    const float* wgt  = (const float*)d_in[3];
    const float* bias = (const float*)d_in[4];
    float* out = (float*)d_out;

    char* ws = (char*)d_ws;
    unsigned short* xT   = (unsigned short*)ws;                      // 4*4096*128*2 = 4194304 B
    unsigned short* Wf   = (unsigned short*)(ws + 4194304);          // 294912*2     =  589824 B
    unsigned short* omWf = (unsigned short*)(ws + 4194304 + 589824); // 36864*2      =   73728 B

    k_pt   <<<1552, 256, 0, stream>>>(x, wgt, om_w, xT, Wf, omWf);
    k_fused<<<512, 256, 0, stream>>>(xT, omWf, om_b, Wf, bias, out);
}

// Round 12
// 44.731 us; speedup vs baseline: 1.0863x; 1.0863x over previous
//
#include <hip/hip_runtime.h>
#include <hip/hip_bf16.h>

typedef _Float16 h4 __attribute__((ext_vector_type(4)));
typedef _Float16 h8 __attribute__((ext_vector_type(8)));
typedef float f32x4 __attribute__((ext_vector_type(4)));

#define CIN 128
#define COUT 256
#define KDIM (CIN*9)   // 1152

// ---------------- merged prep + transpose ----------------
// blocks [0,256): transpose  xT[((b*64+y)*64+x)*128 + c] = fp16(x[b][c][y][x])
// blocks [256,1408): Wf prep, SOURCE-indexed (coalesced wgt reads, scattered 2B writes):
//   g = o*1152 + c*9 + k ; kc = k*128+c ; Wf[(((kc>>5)*16 + (o>>4))*64 + l)*8 + (kc&7)]
//   with l = ((kc>>3)&3)<<4 | (o&15).
// blocks [1408,1552): omWf[(((kch*2 + of)*64 + l)*8 + e)] = fp16(om_w[o][c][k]), 0 if o>=27
__global__ __launch_bounds__(256) void k_pt(const float* __restrict__ x,
                                            const float* __restrict__ wgt,
                                            const float* __restrict__ om_w,
                                            unsigned short* __restrict__ xT,
                                            unsigned short* __restrict__ Wf,
                                            unsigned short* __restrict__ omWf) {
    __shared__ unsigned short tile[64][132];
    const int bid = blockIdx.x;
    if (bid < 256) {
        const int b = bid >> 6, y = bid & 63;
        const float* xp = x + (size_t)b * CIN * 4096 + y * 64;
        const int w = threadIdx.x & 63, cg = threadIdx.x >> 6;
#pragma unroll
        for (int cc = 0; cc < CIN; cc += 4) {
            int c = cc + cg;
            _Float16 hv = (_Float16)xp[(size_t)c * 4096 + w];
            tile[w][c] = *(unsigned short*)&hv;
        }
        __syncthreads();
        unsigned short* orow = xT + (size_t)(b * 4096 + y * 64) * CIN;
#pragma unroll
        for (int i = 0; i < 8; ++i) {
            int j = threadIdx.x + i * 256;
            int w2 = j >> 5, c2 = (j & 31) * 4;
            ushort4 v = *(ushort4*)&tile[w2][c2];
            ((ushort4*)orow)[j] = v;
        }
    } else if (bid < 1408) {
        // source-indexed: g runs linearly over wgt -> coalesced reads
        int g = (bid - 256) * 256 + threadIdx.x;      // < 294912
        int o = g / KDIM, rem = g - o * KDIM;
        int c = rem / 9, k = rem - c * 9;
        int kc = k * 128 + c;
        int kch = kc >> 5, j = kc & 31;
        int l = ((j >> 3) << 4) | (o & 15);
        int e = j & 7, of = o >> 4;
        int f = ((kch * 16 + of) * 64 + l) * 8 + e;
        _Float16 hv = (_Float16)wgt[g];
        Wf[f] = *(unsigned short*)&hv;
    } else {
        int f = (bid - 1408) * 256 + threadIdx.x;   // < 36864
        int e = f & 7, l = (f >> 3) & 63, of = (f >> 9) & 1, kch = f >> 10;
        int o = of * 16 + (l & 15);
        int c = (kch & 3) * 32 + (l >> 4) * 8 + e;
        int k = kch >> 2;
        float v = (o < 27) ? om_w[(size_t)o * KDIM + c * 9 + k] : 0.f;
        _Float16 hv = (_Float16)v;
        omWf[f] = *(unsigned short*)&hv;
    }
}

// ---------------- fused: offset-conv (MFMA) + gather + MFMA GEMM ----------------
// One block per (b, h, half): 32 positions x 256 Cout, 256 threads (4 waves).
// (Exact R9 structure — 44.5 us measured baseline.)
__global__ __launch_bounds__(256, 3) void k_fused(const unsigned short* __restrict__ xT_u,
                                                  const unsigned short* __restrict__ omWf_u,
                                                  const float* __restrict__ om_b,
                                                  const unsigned short* __restrict__ Wf_u,
                                                  const float* __restrict__ bias,
                                                  float* __restrict__ out) {
    const int bid = blockIdx.x;
    const int half = bid & 1, h = (bid >> 1) & 63, b = bid >> 7;
    const int p_base = half * 32;
    const int tid = threadIdx.x;
    const int wv = tid >> 6, lane = tid & 63;
    const int khalf = lane >> 4, lr = lane & 15;

    __shared__ int   s_off[4][288];
    __shared__ float s_wt[4][288];
    __shared__ h8    s_tile[2][32 * 8];   // [buf][row*8 + swizzled slot]
    __shared__ float red[2][32][28];      // omconv partials [tapHalf][pos_local][oc]

    const _Float16* xb = (const _Float16*)xT_u + (size_t)b * (4096 * CIN);

    // ===== Phase 1: offset conv, 4 waves = 2 position-groups x 2 tap-halves =====
    {
        const h8* Af = (const h8*)omWf_u;
        const int pg = wv & 1, kh2 = wv >> 1;
        const int pl = pg * 16 + lr;               // local position 0..31
        const int p = p_base + pl;
        const int k0 = kh2 ? 5 : 0, k1 = kh2 ? 9 : 5;
        f32x4 acc0 = (f32x4){0.f, 0.f, 0.f, 0.f};
        f32x4 acc1 = (f32x4){0.f, 0.f, 0.f, 0.f};
        for (int k = k0; k < k1; ++k) {
            const int ky = k / 3, kx = k - ky * 3;
            const int y = h + ky - 1, xq = p + kx - 1;
            const bool valid = ((unsigned)y < 64u) && ((unsigned)xq < 64u);
            const _Float16* src = xb + ((y * 64 + xq) * CIN);
#pragma unroll
            for (int cg = 0; cg < 4; ++cg) {
                h8 bf = {};
                if (valid) bf = *(const h8*)(src + cg * 32 + khalf * 8);
                const int kch = k * 4 + cg;
                h8 a0 = Af[(kch * 2 + 0) * 64 + lane];
                h8 a1 = Af[(kch * 2 + 1) * 64 + lane];
                acc0 = __builtin_amdgcn_mfma_f32_16x16x32_f16(a0, bf, acc0, 0, 0, 0);
                acc1 = __builtin_amdgcn_mfma_f32_16x16x32_f16(a1, bf, acc1, 0, 0, 0);
            }
        }
        // C layout: col = lr (position), row = khalf*4 + r (+16 for acc1)
#pragma unroll
        for (int r = 0; r < 4; ++r) {
            red[kh2][pl][khalf * 4 + r] = acc0[r];
            int row1 = 16 + khalf * 4 + r;
            if (row1 < 27) red[kh2][pl][row1] = acc1[r];
        }
    }
    __syncthreads();

    // ===== Phase 2: sampling metadata for all (k, pl) =====
    for (int e = tid; e < 288; e += 256) {
        int k = e >> 5, pl = e & 31;
        int p = p_base + pl;
        float offx = red[0][pl][k]      + red[1][pl][k]      + om_b[k];
        float offy = red[0][pl][9 + k]  + red[1][pl][9 + k]  + om_b[9 + k];
        float mv   = red[0][pl][18 + k] + red[1][pl][18 + k] + om_b[18 + k];
        float mask = 1.f / (1.f + __expf(-mv));
        int ky = k / 3, kx = k - ky * 3;
        const float SC = 64.f / 63.f;
        float ix = ((float)(p + kx - 2) + offx) * SC - 0.5f;
        float iy = ((float)(h + ky - 2) + offy) * SC - 0.5f;
        float fx0 = floorf(ix), fy0 = floorf(iy);
        float wx1 = ix - fx0, wx0 = 1.f - wx1;
        float wy1 = iy - fy0, wy0 = 1.f - wy1;
        int x0 = (int)fx0, y0 = (int)fy0;
        int x1 = x0 + 1, y1 = y0 + 1;
        bool vx0 = (unsigned)x0 < 64u, vx1 = (unsigned)x1 < 64u;
        bool vy0 = (unsigned)y0 < 64u, vy1 = (unsigned)y1 < 64u;
        int xc0 = min(max(x0, 0), 63), xc1 = min(max(x1, 0), 63);
        int yc0 = min(max(y0, 0), 63), yc1 = min(max(y1, 0), 63);
        s_off[0][e] = (yc0 * 64 + xc0) * CIN;
        s_off[1][e] = (yc0 * 64 + xc1) * CIN;
        s_off[2][e] = (yc1 * 64 + xc0) * CIN;
        s_off[3][e] = (yc1 * 64 + xc1) * CIN;
        s_wt[0][e] = (vy0 && vx0) ? wy0 * wx0 * mask : 0.f;
        s_wt[1][e] = (vy0 && vx1) ? wy0 * wx1 * mask : 0.f;
        s_wt[2][e] = (vy1 && vx0) ? wy1 * wx0 * mask : 0.f;
        s_wt[3][e] = (vy1 && vx1) ? wy1 * wx1 * mask : 0.f;
    }
    __syncthreads();

    // ===== Phase 3: pipelined gather + MFMA GEMM (18 chunks of 64 ch) =====
    const int p  = tid >> 3;      // local gather position 0..31
    const int ci = tid & 7;       // 8-channel slot
    const h8* Wf8 = (const h8*)Wf_u;
    const int wslot = ci ^ (p & 7);

    f32x4 acc[4][2];              // [of-frag i][pos-frag pf]
#pragma unroll
    for (int i = 0; i < 4; ++i)
#pragma unroll
        for (int j = 0; j < 2; ++j) acc[i][j] = (f32x4){0.f, 0.f, 0.f, 0.f};

    // prologue: gather chunk 0 into buf 0
    {
        const int e0 = p;                     // tap 0
        const int cb = ci * 8;                // chalf 0
        h8 v00 = *(const h8*)(xb + s_off[0][e0] + cb);
        h8 v01 = *(const h8*)(xb + s_off[1][e0] + cb);
        h8 v10 = *(const h8*)(xb + s_off[2][e0] + cb);
        h8 v11 = *(const h8*)(xb + s_off[3][e0] + cb);
        const float m00 = s_wt[0][e0], m01 = s_wt[1][e0], m10 = s_wt[2][e0], m11 = s_wt[3][e0];
        h8 pk;
#pragma unroll
        for (int j = 0; j < 8; ++j) {
            float r = m00 * (float)v00[j] + m01 * (float)v01[j]
                    + m10 * (float)v10[j] + m11 * (float)v11[j];
            pk[j] = (_Float16)r;
        }
        s_tile[0][p * 8 + wslot] = pk;
    }
    __syncthreads();

    for (int ch = 0; ch < 18; ++ch) {
        const int cur = ch & 1;
        const int nxt = ch + 1;

        h8 v00, v01, v10, v11;
        float m00, m01, m10, m11;
        if (nxt < 18) {
            const int kn = nxt >> 1;
            const int e = kn * 32 + p;
            const int cb = (nxt & 1) * 64 + ci * 8;
            v00 = *(const h8*)(xb + s_off[0][e] + cb);
            v01 = *(const h8*)(xb + s_off[1][e] + cb);
            v10 = *(const h8*)(xb + s_off[2][e] + cb);
            v11 = *(const h8*)(xb + s_off[3][e] + cb);
            m00 = s_wt[0][e]; m01 = s_wt[1][e]; m10 = s_wt[2][e]; m11 = s_wt[3][e];
        }

        const int k = ch >> 1, chalf = ch & 1;
#pragma unroll
        for (int ks = 0; ks < 2; ++ks) {
            const int kch = k * 4 + chalf * 2 + ks;
            h8 a[4];
#pragma unroll
            for (int i = 0; i < 4; ++i)
                a[i] = Wf8[(kch * 16 + wv * 4 + i) * 64 + lane];
            h8 bf[2];
#pragma unroll
            for (int pf = 0; pf < 2; ++pf) {
                const int row = pf * 16 + lr;
                bf[pf] = s_tile[cur][row * 8 + ((ks * 4 + khalf) ^ (row & 7))];
            }
#pragma unroll
            for (int i = 0; i < 4; ++i)
#pragma unroll
                for (int pf = 0; pf < 2; ++pf)
                    acc[i][pf] = __builtin_amdgcn_mfma_f32_16x16x32_f16(a[i], bf[pf], acc[i][pf], 0, 0, 0);
        }

        if (nxt < 18) {
            h8 pk;
#pragma unroll
            for (int j = 0; j < 8; ++j) {
                float r = m00 * (float)v00[j] + m01 * (float)v01[j]
                        + m10 * (float)v10[j] + m11 * (float)v11[j];
                pk[j] = (_Float16)r;
            }
            s_tile[cur ^ 1][p * 8 + wslot] = pk;
        }
        __syncthreads();
    }

    // epilogue: C[o = wv*64 + i*16 + khalf*4 + r][pos = p_base + pf*16 + lr]
    float* outb = out + (size_t)b * COUT * 4096 + h * 64 + p_base;
#pragma unroll
    for (int i = 0; i < 4; ++i) {
#pragma unroll
        for (int r = 0; r < 4; ++r) {
            const int o = wv * 64 + i * 16 + khalf * 4 + r;
            const float bo = bias[o];
            float* orow = outb + (size_t)o * 4096;
#pragma unroll
            for (int pf = 0; pf < 2; ++pf)
                orow[pf * 16 + lr] = acc[i][pf][r] + bo;
        }
    }
}

extern "C" void kernel_launch(void* const* d_in, const int* in_sizes, int n_in,
                              void* d_out, int out_size, void* d_ws, size_t ws_size,
                              hipStream_t stream) {
    const float* x    = (const float*)d_in[0];
    const float* om_w = (const float*)d_in[1];
    const float* om_b = (const float*)d_in[2];
    const float* wgt  = (const float*)d_in[3];
    const float* bias = (const float*)d_in[4];
    float* out = (float*)d_out;

    char* ws = (char*)d_ws;
    unsigned short* xT   = (unsigned short*)ws;                      // 4*4096*128*2 = 4194304 B
    unsigned short* Wf   = (unsigned short*)(ws + 4194304);          // 294912*2     =  589824 B
    unsigned short* omWf = (unsigned short*)(ws + 4194304 + 589824); // 36864*2      =   73728 B

    k_pt   <<<1552, 256, 0, stream>>>(x, wgt, om_w, xT, Wf, omWf);
    k_fused<<<512, 256, 0, stream>>>(xT, omWf, om_b, Wf, bias, out);
}